// Round 3
// baseline (429.798 us; speedup 1.0000x reference)
//
#include <hip/hip_runtime.h>
#include <math.h>

#define NCLS 81
#define NANCH 8732
#define NB 64
#define BUCKET_STRIDE 16     // 64 B cacheline spread for int buckets
#define HSTRIDE 257          // bank-decorrelated histogram copy stride (ints)
#define NCONF_BLK 8732       // 64 anchors per block (8732*64 == 64*8732 anchors)
#define NLOC_BLK  2240       // 35 chunks * 64 batch rows

// ---------------- Kernel A: fused conf loss (LDS-free) + loc loss ----------------
// conf: one-hot trick -> conf_loss = lse - dot(x,g); pos <=> g[0]==0.
// No LDS, no __syncthreads: each anchor owned by 4 lanes streaming float4.
// Rows are 324 B (= 4 mod 16): skip h=(4-anchor)&3 head floats so vector
// loads are 16B-aligned; <=5 leftover elements handled scalar.
__global__ __launch_bounds__(256) void conf_loc_kernel(
    const float* __restrict__ pred_conf,
    const float* __restrict__ gt_conf,
    const float* __restrict__ pred_loc,
    const float* __restrict__ gt_loc,
    float* __restrict__ cl_out,       // [B*N] cl_neg (0 for positives)
    int* __restrict__ pos_buckets,    // [64*BUCKET_STRIDE], pre-zeroed
    float* __restrict__ row_pos,      // [128] per-row positive-loss sums, pre-zeroed
    float* __restrict__ out)          // loc part accumulates out[64+b]
{
    const int tid = threadIdx.x;
    const int lane = tid & 63, wid = tid >> 6;

    if (blockIdx.x >= NCONF_BLK) {
        // ---- loc part: smooth-L1-quirk loss, one atomic per wave ----
        const int bid = blockIdx.x - NCONF_BLK;
        const int b = bid & 63;         // consecutive blocks -> different b (atomic spread)
        const int chunk = bid >> 6;     // 0..34
        const int idx = chunk * 256 + tid;
        float local = 0.f;
        if (idx < NANCH) {
            const float4* p = (const float4*)(pred_loc + (size_t)b * (NANCH * 4));
            const float4* g = (const float4*)(gt_loc + (size_t)b * (NANCH * 4));
            float4 pv = p[idx];
            float4 gv = g[idx];
            float a0 = fabsf(pv.x - gv.x), a1 = fabsf(pv.y - gv.y);
            float a2 = fabsf(pv.z - gv.z), a3 = fabsf(pv.w - gv.w);
            local  = (a0 > 1.f) ? (a0 - 0.5f) : 0.f;
            local += (a1 > 1.f) ? (a1 - 0.5f) : 0.f;
            local += (a2 > 1.f) ? (a2 - 0.5f) : 0.f;
            local += (a3 > 1.f) ? (a3 - 0.5f) : 0.f;
        }
        for (int off = 32; off; off >>= 1) local += __shfl_xor(local, off);
        if (lane == 0 && local != 0.f) atomicAdd(&out[64 + b], local);
        return;
    }

    // ---- conf part ----
    const int a_loc = tid >> 2;                 // anchor within block
    const int q = tid & 3;                      // lane within anchor
    const int anchor = blockIdx.x * 64 + a_loc; // < 558848
    const int h = (4 - (anchor & 3)) & 3;       // head floats to skip for alignment
    const size_t fbase = (size_t)anchor * NCLS;
    const float* xr = pred_conf + fbase;
    const float* gr = gt_conf + fbase;
    const float4* x4 = (const float4*)(xr + h); // 16B-aligned by construction
    const float4* g4 = (const float4*)(gr + h);
    const int n4 = (NCLS - h) >> 2;             // 19 or 20 aligned float4s

    float se = 0.f, dot = 0.f, g0v = 1.0f;
#pragma unroll
    for (int j = 0; j < 5; ++j) {
        const int k = 4 * j + q;                // 4 lanes -> 64 B contiguous per anchor
        if (k < n4) {
            float4 x = x4[k];
            float4 g = g4[k];
            se  += __expf(x.x) + __expf(x.y) + __expf(x.z) + __expf(x.w);
            dot += x.x * g.x + x.y * g.y + x.z * g.z + x.w * g.w;
            if (j == 0 && q == 0 && h == 0) g0v = g.x;   // class 0 in vector path
        }
    }
    // leftovers: h head floats + (81-h-4*n4) tail floats; cnt is 1 or 5
    const int cnt = NCLS - 4 * n4;
    for (int i = q; i < cnt; i += 4) {
        const int e = (i < h) ? i : (h + 4 * n4 + (i - h));
        float xv = xr[e], gv = gr[e];
        se  += __expf(xv);
        dot += xv * gv;
        if (e == 0) g0v = gv;                   // class 0 in leftover path (q==0 owns i=0)
    }

    // reduce across the anchor's 4 lanes
    se  += __shfl_xor(se, 1);  dot += __shfl_xor(dot, 1);
    se  += __shfl_xor(se, 2);  dot += __shfl_xor(dot, 2);
    const float lse = __logf(se);
    const float conf_loss = lse - dot;          // dot == x[label] bit-exact (one-hot)

    bool posf = false;
    if (q == 0) {
        posf = (g0v == 0.0f);
        cl_out[anchor] = posf ? 0.0f : conf_loss;
    }

    // per-wave reductions: positive-loss row sums + positive count
    const int b = anchor / NANCH;
    float contrib = (q == 0 && posf) ? conf_loss : 0.0f;
    int pc = (q == 0 && posf) ? 1 : 0;
    const int bF = __builtin_amdgcn_readfirstlane(b);
    float c0 = (b == bF) ? contrib : 0.0f;
    float c1 = contrib - c0;                    // spillover if wave crosses a row boundary
    for (int off = 32; off; off >>= 1) {
        c0 += __shfl_xor(c0, off);
        c1 += __shfl_xor(c1, off);
        pc += __shfl_xor(pc, off);
    }
    if (lane == 0) {
        if (c0 != 0.f) atomicAdd(&row_pos[bF], c0);
        if (c1 != 0.f) atomicAdd(&row_pos[bF + 1], c1);
        if (pc) atomicAdd(&pos_buckets[(((blockIdx.x << 2) | wid) & 63) * BUCKET_STRIDE], pc);
    }
}

// ---------------- Kernel B: hard-negative mining + conf total ----------------
// grid = 64 rows, block = 1024. Radix-256 select over float bits, 4 rounds.
// Round 0: ballot match-any (values cluster into 1-3 exponent bins -> ~3 loop
// iters, one atomic per distinct bin per wave). Rounds 1-3: plain atomics,
// 4 copies at stride 257 (bank-decorrelated).
__global__ __launch_bounds__(1024) void select_kernel(
    const float* __restrict__ val,
    const int* __restrict__ pos_buckets,
    const float* __restrict__ row_pos,
    float* __restrict__ out)
{
    __shared__ float cl[NANCH];
    __shared__ int hist[4 * HSTRIDE];
    __shared__ int wsum[16];
    __shared__ float fred[16];
    __shared__ int sh_numpos;
    __shared__ unsigned int sh_prefix;
    __shared__ int sh_k, sh_thr;

    const int b = blockIdx.x;
    const int tid = threadIdx.x;
    const int lane = tid & 63, w = tid >> 6;
    const int hofs = (w & 3) * HSTRIDE;
    const float* row = val + b * NANCH;

    if (tid < 64) {
        int v = pos_buckets[tid * BUCKET_STRIDE];
        for (int off = 32; off; off >>= 1) v += __shfl_xor(v, off);
        if (tid == 0) sh_numpos = v;
    }
    for (int i = tid; i < NANCH; i += 1024) cl[i] = row[i];
    __syncthreads();

    int k = 3 * sh_numpos;               // ref: int(3.0 * num_pos), global scalar
    if (k > NANCH - 1) k = NANCH - 1;
    if (k < 0) k = 0;

    unsigned int prefix = 0u;
    for (int r = 0; r < 4; ++r) {
        const int shift = 24 - 8 * r;
        const unsigned int maskHigh = (r == 0) ? 0u : (0xFFFFFFFFu << (shift + 8));
        for (int j = tid; j < 4 * HSTRIDE; j += 1024) hist[j] = 0;
        __syncthreads();
        if (r == 0) {
            // wave-aggregated histogram of the exponent byte
            for (int i0 = 0; i0 < 9216; i0 += 1024) {
                int i = i0 + tid;
                bool valid = (i < NANCH);
                unsigned int u = valid ? __float_as_uint(cl[i]) : 0u;
                int bin = (int)(u >> 24);
                unsigned long long act = __ballot(valid);
                while (act) {
                    int leader = (int)__ffsll((long long)act) - 1;
                    int lbin = __shfl(bin, leader);
                    unsigned long long sm = __ballot(valid && (bin == lbin));
                    if (lane == leader) atomicAdd(&hist[hofs + lbin], (int)__popcll(sm));
                    act &= ~sm;
                }
            }
        } else {
            for (int i = tid; i < NANCH; i += 1024) {
                unsigned int u = __float_as_uint(cl[i]);
                if ((u & maskHigh) == prefix)
                    atomicAdd(&hist[hofs + ((u >> shift) & 0xFF)], 1);
            }
        }
        __syncthreads();
        int h = 0, v = 0;
        if (tid < 256) {
            h = hist[tid] + hist[HSTRIDE + tid] + hist[2 * HSTRIDE + tid]
              + hist[3 * HSTRIDE + tid];
            v = h;
#pragma unroll
            for (int off = 1; off < 64; off <<= 1) {
                int u2 = __shfl_up(v, off);
                if (lane >= off) v += u2;
            }
            if (lane == 63) wsum[w] = v;
        }
        __syncthreads();
        if (tid < 256) {
            int add = 0;
            for (int i = 0; i < w; ++i) add += wsum[i];
            int incl = v + add, excl = incl - h;
            if (excl <= k && k < incl) {
                sh_prefix = prefix | ((unsigned int)tid << shift);
                sh_k = k - excl;
            }
        }
        __syncthreads();
        prefix = sh_prefix;
        k = sh_k;
        __syncthreads();
    }
    const unsigned int T = prefix;

    // stable (index-order) resolution of the k-th equal element
    const int CHUNK = 9;
    int lo = tid * CHUNK; if (lo > NANCH) lo = NANCH;
    int hi = lo + CHUNK; if (hi > NANCH) hi = NANCH;
    int cnt = 0;
    for (int i = lo; i < hi; ++i)
        cnt += (__float_as_uint(cl[i]) == T);
    int v2 = cnt;
#pragma unroll
    for (int off = 1; off < 64; off <<= 1) {
        int u2 = __shfl_up(v2, off);
        if (lane >= off) v2 += u2;
    }
    if (lane == 63) wsum[w] = v2;
    __syncthreads();
    if (tid < 16) {
        int s = wsum[tid];
#pragma unroll
        for (int off = 1; off < 16; off <<= 1) {
            int u2 = __shfl_up(s, off);
            if (lane >= off) s += u2;
        }
        wsum[tid] = s;
    }
    __syncthreads();
    {
        int add = (w == 0) ? 0 : wsum[w - 1];
        int incl = v2 + add, excl = incl - cnt;
        if (excl <= k && k < incl) {
            int need = k - excl, idx = NANCH - 1;
            for (int i = lo; i < hi; ++i) {
                if (__float_as_uint(cl[i]) == T) {
                    if (need == 0) { idx = i; break; }
                    --need;
                }
            }
            sh_thr = idx;
        }
    }
    __syncthreads();

    const float thr = (float)sh_thr;     // quirk: threshold is the argsort INDEX
    float local = 0.f;
    for (int i = tid; i < NANCH; i += 1024) {
        float c = cl[i];
        if (c > thr) local += c;
    }
    for (int off = 32; off; off >>= 1) local += __shfl_xor(local, off);
    if (lane == 0) fred[w] = local;
    __syncthreads();
    if (tid == 0) {
        float t = row_pos[b];
        for (int i = 0; i < 16; ++i) t += fred[i];
        out[b] = t;
    }
}

extern "C" void kernel_launch(void* const* d_in, const int* in_sizes, int n_in,
                              void* d_out, int out_size, void* d_ws, size_t ws_size,
                              hipStream_t stream) {
    const float* pred_conf = (const float*)d_in[0];
    const float* pred_loc  = (const float*)d_in[1];
    const float* gt_conf   = (const float*)d_in[2];
    const float* gt_loc    = (const float*)d_in[3];
    float* out = (float*)d_out;

    int*   pos_buckets = (int*)d_ws;                     // [0, 4096)
    float* row_pos     = (float*)((char*)d_ws + 4096);   // [4096, 4608)
    float* vals        = (float*)((char*)d_ws + 8192);   // [64*8732] floats

    hipMemsetAsync(d_ws, 0, 8192, stream);
    hipMemsetAsync(d_out, 0, 128 * sizeof(float), stream);

    conf_loc_kernel<<<NCONF_BLK + NLOC_BLK, 256, 0, stream>>>(
        pred_conf, gt_conf, pred_loc, gt_loc, vals, pos_buckets, row_pos, out);
    select_kernel<<<NB, 1024, 0, stream>>>(vals, pos_buckets, row_pos, out);
}